// Round 6
// baseline (698.523 us; speedup 1.0000x reference)
//
#include <hip/hip_runtime.h>

// EncoderDecoderLSTM on MI355X — R21: BARRIER-FREE 3-wave pipeline.
// R20 post-mortem: cutting B2's chain 4->2 and raising occupancy to 34%
// changed nothing -> the 1788cyc/slot vs ~350cyc chain gap is the 12-wave
// phase-lock rendezvous itself (R4/R5/R7/R9/R19/R20 all consistent).
// New structure: ONE WAVE OWNS ONE RECURRENCE -> its step needs only
// lgkmcnt on its own LDS h round-trip, no s_barrier at all.
//   W0 (wave0): layer0 full width. 16 tiles (4 unit-blocks x 4 gates),
//               32 MFMA + 8 act2 per step. h0 ring[2], self-synced.
//   W2 (wave2): pp = b1 + Wih1*h0 (32 MFMA, no act) -> pp ring[2].
//   W1 (wave1): h1 = act(pp + Whh1*h1) (32 MFMA + 8 act2), h1 ring[2];
//               decoder FC + dins feedback.
// Handoff: LDS progress counters (flg), producer does lgkmcnt(0) fence ->
// lane0 volatile flag store; consumer volatile spin. Backpressure keeps
// ring slots safe. Dependencies point backward in time -> deadlock-free.
// Exact same per-gate summation order as R20 (pp exact f32 round-trip)
// -> BIT-EXACT: absmax must be exactly 0.0002441406 (canary).
// Carryovers: chain-minimized act2 (R18), swapped MFMA D=W*h^T, b64
// h-store, bias/pp via MFMA C-operand, lane-scalar x term, pre-scaled
// single-f16 weights, c fp32 in regs, HPAD=72, pp XOR-swizzle.
// 192 threads/block, grid 256 (1 block/CU, waves on 3 of 4 SIMDs),
// ~320 VGPR/wave (1 wave/SIMD — all we need).

typedef _Float16 f16x8 __attribute__((ext_vector_type(8)));
typedef _Float16 f16x4 __attribute__((ext_vector_type(4)));
typedef float    f32x4 __attribute__((ext_vector_type(4)));
typedef float    f32x2 __attribute__((ext_vector_type(2)));

static constexpr int T_ENC = 365;
static constexpr int HZ    = 7;
static constexpr int TT    = T_ENC + HZ;   // 372 pipeline steps
static constexpr int BT    = 16;           // batch tile per block
static constexpr int HPAD  = 72;           // padded f16 row stride (144 B)

static constexpr float LOG2E  = 1.442695040888963f;
static constexpr float SCL_I  = -LOG2E;
static constexpr float SCL_G  = 2.0f * LOG2E;

#if __has_builtin(__builtin_amdgcn_exp2f)
__device__ __forceinline__ float fexp2(float x) { return __builtin_amdgcn_exp2f(x); }
#else
__device__ __forceinline__ float fexp2(float x) { return __exp2f(x); }
#endif
#if __has_builtin(__builtin_amdgcn_rcpf)
__device__ __forceinline__ float frcp(float x) { return __builtin_amdgcn_rcpf(x); }
#else
__device__ __forceinline__ float frcp(float x) { return 1.0f / x; }
#endif

__device__ __forceinline__ f32x4 mm1(f16x8 w, f16x8 a, f32x4 acc) {
  return __builtin_amdgcn_mfma_f32_16x16x32_f16(w, a, acc, 0, 0, 0);
}

// Drain this wave's LDS ops (all lanes of all its ds instructions), then
// compile-barrier so the following flag store cannot be hoisted.
__device__ __forceinline__ void fence_lds() {
  asm volatile("s_waitcnt lgkmcnt(0)" ::: "memory");
}
__device__ __forceinline__ void waitge(volatile int* f, int target) {
  while (*f < target) { }
}

__global__ __launch_bounds__(192, 1)
void lstm_fused(const float* __restrict__ x,
                const float* __restrict__ eWih0, const float* __restrict__ eWhh0,
                const float* __restrict__ eb0,
                const float* __restrict__ eWih1, const float* __restrict__ eWhh1,
                const float* __restrict__ eb1,
                const float* __restrict__ dWih0, const float* __restrict__ dWhh0,
                const float* __restrict__ db0,
                const float* __restrict__ dWih1, const float* __restrict__ dWhh1,
                const float* __restrict__ db1,
                const float* __restrict__ fcW, const float* __restrict__ fcb,
                float* __restrict__ out)
{
  __shared__ __align__(16) float    xs[T_ENC * BT];        // x transposed [t][b]
  __shared__ __align__(16) _Float16 h0r[2][BT * HPAD];     // h0 ring
  __shared__ __align__(16) _Float16 h1r[2][BT * HPAD];     // h1 ring
  __shared__ __align__(16) float    pp[2][16 * 256];       // partial ring (swizzled)
  __shared__ __align__(16) float    dins[BT];
  __shared__ int flg[4];   // 0: W0 steps done  1: W2 done  2: W1 done  3: FC done

  const int tid  = threadIdx.x;
  const int lane = tid & 63;
  const int wv   = tid >> 6;        // 0 = W0(L0), 1 = W1(L1+FC), 2 = W2(pp)
  const int n    = lane & 15;       // D col = batch row ; weight-fragment A-row
  const int q    = lane >> 4;       // quad: D rows 4q..4q+3 ; k-chunk for frags
  const int b0g  = blockIdx.x * BT;
  const int nH   = n * HPAD;
  const int ppswz = (n & 7) << 2;
  const int ppn   = n << 8;

  // ---- prologue: stage x, zero rings/flags ----
  for (int i = tid; i < T_ENC * BT; i += 192) {
    int b = i / T_ENC;
    int t = i - b * T_ENC;
    xs[t * BT + b] = x[(b0g + b) * T_ENC + t];
  }
  for (int i = tid; i < 2 * BT * HPAD; i += 192) {
    ((_Float16*)h0r)[i] = (_Float16)0.f;
    ((_Float16*)h1r)[i] = (_Float16)0.f;
  }
  if (tid < BT) dins[tid] = 0.f;
  if (tid < 4)  flg[tid] = 0;

  // ---- per-role weight registers (pre-scaled single-f16 planes) ----
  // WA[wb][ti][kc]: W0 = Whh0 ; W1 = Whh1 ; W2 = Wih1.
  // biasq: W0 = b0 ; W2 = b1 (C-seed).  wih0q: W0 only.
  f16x8 WA[4][4][2];
  f32x4 biasq[4][4], wih0q[4][4];
  f32x2 cp[4][2] = {};   // c-state per unit-block, row pairs

  auto gscale = [&](int ti) { return (ti == 2) ? SCL_G : SCL_I; };
  auto cvtrow = [&](const float* p, float s, f16x8& w) {
    #pragma unroll
    for (int j = 0; j < 8; ++j) w[j] = (_Float16)(p[j] * s);
  };
  auto loadFrags = [&](const float* W_) {
    #pragma unroll
    for (int wb = 0; wb < 4; ++wb)
      #pragma unroll
      for (int ti = 0; ti < 4; ++ti) {
        const float s = gscale(ti);
        const int rw = (ti * 4 + wb) * 16 + n;
        #pragma unroll
        for (int kc = 0; kc < 2; ++kc)
          cvtrow(W_ + rw * 64 + kc * 32 + q * 8, s, WA[wb][ti][kc]);
      }
  };
  auto loadBias = [&](const float* b_) {
    #pragma unroll
    for (int wb = 0; wb < 4; ++wb)
      #pragma unroll
      for (int ti = 0; ti < 4; ++ti) {
        const float s = gscale(ti);
        const int rq = (ti * 4 + wb) * 16 + (q << 2);
        #pragma unroll
        for (int rr = 0; rr < 4; ++rr) biasq[wb][ti][rr] = b_[rq + rr] * s;
      }
  };
  auto loadWih0 = [&](const float* W_) {
    #pragma unroll
    for (int wb = 0; wb < 4; ++wb)
      #pragma unroll
      for (int ti = 0; ti < 4; ++ti) {
        const float s = gscale(ti);
        const int rq = (ti * 4 + wb) * 16 + (q << 2);
        #pragma unroll
        for (int rr = 0; rr < 4; ++rr) wih0q[wb][ti][rr] = W_[rq + rr] * s;
      }
  };

  if (wv == 0)      { loadFrags(eWhh0); loadBias(eb0); loadWih0(eWih0); }
  else if (wv == 1) { loadFrags(eWhh1); }
  else              { loadFrags(eWih1); loadBias(eb1); }

  // Chain-minimized packed activation (R18).
  auto act2 = [&](f32x2 a0, f32x2 a1, f32x2 a2, f32x2 a3, f32x2& c) -> f32x2 {
    f32x2 ei, ef, eg, eo;
    ei.x = fexp2(a0.x); ei.y = fexp2(a0.y);
    ef.x = fexp2(a1.x); ef.y = fexp2(a1.y);
    eg.x = fexp2(a2.x); eg.y = fexp2(a2.y);
    eo.x = fexp2(a3.x); eo.y = fexp2(a3.y);
    const f32x2 one = {1.f, 1.f};
    f32x2 di = one + ei, df = one + ef, dg = one + eg, dd = one + eo;
    f32x2 dif = di * df;
    f32x2 dic = di * c;
    f32x2 t1  = dif * dg;
    f32x2 nd  = eg * df - df;
    f32x2 pc  = dic * dg;
    f32x2 s   = pc + nd;
    const f32x2 sclg = {SCL_G, SCL_G};
    f32x2 sg  = sclg * s;
    f32x2 R1; R1.x = frcp(t1.x); R1.y = frcp(t1.y);
    c = R1 * s;
    f32x2 ca = R1 * sg;
    const f32x2 cap = {20.f, 20.f};
    ca.x = fminf(ca.x, cap.x); ca.y = fminf(ca.y, cap.y);
    f32x2 ec; ec.x = fexp2(ca.x); ec.y = fexp2(ca.y);
    f32x2 t2 = ec * dd + dd;
    f32x2 nc = ec - one;
    f32x2 R2; R2.x = frcp(t2.x); R2.y = frcp(t2.y);
    return nc * R2;
  };

  // act + b64 h publish for one unit-block wb.
  auto epilog_wb = [&](const f32x4* g, f32x2* cpw, _Float16* O, int wb) {
    f32x2 h2[2];
    #pragma unroll
    for (int pr = 0; pr < 2; ++pr) {
      f32x2 a0 = {g[0][2 * pr], g[0][2 * pr + 1]};
      f32x2 a1 = {g[1][2 * pr], g[1][2 * pr + 1]};
      f32x2 a2 = {g[2][2 * pr], g[2][2 * pr + 1]};
      f32x2 a3 = {g[3][2 * pr], g[3][2 * pr + 1]};
      h2[pr] = act2(a0, a1, a2, a3, cpw[pr]);
    }
    f16x4 hv;
    hv[0] = (_Float16)h2[0].x; hv[1] = (_Float16)h2[0].y;
    hv[2] = (_Float16)h2[1].x; hv[3] = (_Float16)h2[1].y;
    *(f16x4*)(O + nH + (wb << 4) + (q << 2)) = hv;
  };

  // ================= role loops (no __syncthreads below) =================
  __syncthreads();

  if (wv == 0) {
    // ---- W0: layer0 recurrence, full 64 units ----
    #pragma unroll 1
    for (int t = 0; t < TT; ++t) {
      if (t == T_ENC) { loadFrags(dWhh0); loadBias(db0); loadWih0(dWih0); }
      float xb;
      if (t < T_ENC) {
        xb = xs[t * BT + n];
      } else {
        waitge((volatile int*)&flg[3], t - T_ENC);   // FC(hz-1) done -> dins ready
        xb = dins[n];
      }
      if (t >= 2) waitge((volatile int*)&flg[1], t - 1);   // W2 consumed h0(t-2)
      const _Float16* hp = h0r[(t + 1) & 1] + nH;          // h0(t-1)
      _Float16* O = h0r[t & 1];
      f16x8 a0 = *(const f16x8*)(hp + q * 8);
      f16x8 a1 = *(const f16x8*)(hp + 32 + q * 8);
      const f32x4 xbv = {xb, xb, xb, xb};
      #pragma unroll
      for (int wb = 0; wb < 4; ++wb) {
        f32x4 g[4];
        #pragma unroll
        for (int ti = 0; ti < 4; ++ti) {
          f32x4 ci = biasq[wb][ti] + xbv * wih0q[wb][ti];
          f32x4 a = mm1(WA[wb][ti][0], a0, ci);
          a = mm1(WA[wb][ti][1], a1, a);
          g[ti] = a;
        }
        epilog_wb(g, cp[wb], O, wb);
      }
      fence_lds();
      if (lane == 0) *(volatile int*)&flg[0] = t + 1;
    }
  } else if (wv == 2) {
    // ---- W2: pp producer ----
    #pragma unroll 1
    for (int t = 0; t < TT; ++t) {
      if (t == T_ENC) { loadFrags(dWih1); loadBias(db1); }
      waitge((volatile int*)&flg[0], t + 1);               // h0(t) ready
      if (t >= 2) waitge((volatile int*)&flg[2], t - 1);   // W1 consumed pp(t-2)
      const _Float16* hp = h0r[t & 1] + nH;
      float* ppb = pp[t & 1];
      f16x8 a0 = *(const f16x8*)(hp + q * 8);
      f16x8 a1 = *(const f16x8*)(hp + 32 + q * 8);
      #pragma unroll
      for (int wb = 0; wb < 4; ++wb) {
        #pragma unroll
        for (int ti = 0; ti < 4; ++ti) {
          f32x4 p = mm1(WA[wb][ti][0], a0, biasq[wb][ti]);
          p = mm1(WA[wb][ti][1], a1, p);
          const int rq = ((ti * 4 + wb) << 4) + (q << 2);
          *(f32x4*)&ppb[ppn + (rq ^ ppswz)] = p;
        }
      }
      fence_lds();
      if (lane == 0) *(volatile int*)&flg[1] = t + 1;
    }
  } else {
    // ---- W1: layer1 recurrence + decoder FC ----
    float fcw[16];
    float fcb0 = 0.f;
    #pragma unroll 1
    for (int t = 0; t < TT; ++t) {
      if (t == T_ENC) {
        loadFrags(dWhh1);
        #pragma unroll
        for (int j = 0; j < 16; ++j) fcw[j] = fcW[q * 16 + j];
        fcb0 = fcb[0];
      }
      waitge((volatile int*)&flg[1], t + 1);               // pp(t) ready
      const _Float16* hp = h1r[(t + 1) & 1] + nH;          // h1(t-1) (own)
      _Float16* O = h1r[t & 1];
      const float* ppb = pp[t & 1];
      f16x8 a0 = *(const f16x8*)(hp + q * 8);
      f16x8 a1 = *(const f16x8*)(hp + 32 + q * 8);
      #pragma unroll
      for (int wb = 0; wb < 4; ++wb) {
        f32x4 g[4];
        #pragma unroll
        for (int ti = 0; ti < 4; ++ti) {
          const int rq = ((ti * 4 + wb) << 4) + (q << 2);
          f32x4 ci = *(const f32x4*)&ppb[ppn + (rq ^ ppswz)];
          f32x4 a = mm1(WA[wb][ti][0], a0, ci);
          a = mm1(WA[wb][ti][1], a1, a);
          g[ti] = a;
        }
        epilog_wb(g, cp[wb], O, wb);
      }
      fence_lds();
      if (lane == 0) *(volatile int*)&flg[2] = t + 1;
      if (t >= T_ENC) {
        // FC for hz = t - T_ENC on the just-written h1 (drained by fence).
        const int hz = t - T_ENC;
        const _Float16* Hh = h1r[t & 1];
        f16x8 hh0 = *(const f16x8*)(Hh + nH + q * 16);
        f16x8 hh1 = *(const f16x8*)(Hh + nH + q * 16 + 8);
        float pacc = 0.f;
        #pragma unroll
        for (int j = 0; j < 8; ++j) pacc += fcw[j] * (float)hh0[j];
        #pragma unroll
        for (int j = 0; j < 8; ++j) pacc += fcw[8 + j] * (float)hh1[j];
        pacc += __shfl_down(pacc, 32);
        pacc += __shfl_down(pacc, 16);
        if (lane < BT) {
          pacc += fcb0;
          out[(b0g + lane) * HZ + hz] = pacc;
          dins[lane] = pacc;
        }
        fence_lds();
        if (lane == 0) *(volatile int*)&flg[3] = hz + 1;
      }
    }
  }
}

extern "C" void kernel_launch(void* const* d_in, const int* in_sizes, int n_in,
                              void* d_out, int out_size, void* d_ws, size_t ws_size,
                              hipStream_t stream) {
  (void)in_sizes; (void)n_in; (void)d_ws; (void)ws_size; (void)out_size;
  const float* x     = (const float*)d_in[0];
  const float* eWih0 = (const float*)d_in[1];
  const float* eWhh0 = (const float*)d_in[2];
  const float* eb0   = (const float*)d_in[3];
  const float* eWih1 = (const float*)d_in[4];
  const float* eWhh1 = (const float*)d_in[5];
  const float* eb1   = (const float*)d_in[6];
  const float* dWih0 = (const float*)d_in[7];
  const float* dWhh0 = (const float*)d_in[8];
  const float* db0   = (const float*)d_in[9];
  const float* dWih1 = (const float*)d_in[10];
  const float* dWhh1 = (const float*)d_in[11];
  const float* db1   = (const float*)d_in[12];
  const float* fcW   = (const float*)d_in[13];
  const float* fcb   = (const float*)d_in[14];
  float* out = (float*)d_out;

  dim3 grid(4096 / BT);   // 256 blocks = 1/CU
  dim3 block(192);        // 3 waves: W0 / W1 / W2, each on its own SIMD
  hipLaunchKernelGGL(lstm_fused, grid, block, 0, stream,
                     x, eWih0, eWhh0, eb0, eWih1, eWhh1, eb1,
                     dWih0, dWhh0, db0, dWih1, dWhh1, db1, fcW, fcb, out);
}